// Round 8
// baseline (1565.382 us; speedup 1.0000x reference)
//
#include <hip/hip_runtime.h>

// ---------------- problem constants ----------------
#define L_      8838           // LATENT
#define LP_     9216           // padded row length (u8 bytes per G row; bf16 per LDS vec)
#define MPOW    8              // highest kept power of G
#define NSLOT   (MPOW + 1)
#define NFULL   2              // passes 1..NFULL read hi+lo; later passes hi-only
#define CT      512            // threads per block (8 waves)
#define CWGRID  512            // chain grid: 2 blocks/CU co-resident
#define CWAVES  (CWGRID * (CT / 64))   // 4096
#define CEXTRA  (L_ - 2 * CWAVES)      // 646 striped extra rows
#define P0GRID  1024                   // pass0 grid
#define P0WAVES (P0GRID * (CT / 64))   // 8192
#define P0EXTRA (L_ - P0WAVES)         // 646
#define P0DEPTH 12                     // pass0 load pipeline depth (16B each)

// quantization: q16 = clamp(rn((g + BOFF)/D16), 0, 65535), g = q16*D16 - BOFF
// hi = rn(q16/256) (unbiased hi-only recon), lo = q16 - 256*hi + 128
#define BOFF 6.0e-4f
#define D16  (BOFF / 32768.0f)
#define DHI  (BOFF / 128.0f)           // 256 * D16 ; exact zero recon for pad cols
#define C2   (BOFF + 128.0f * D16)
#define QS   (32768.0f / BOFF)

typedef float          f32x4 __attribute__((ext_vector_type(4)));
typedef float          f32x2 __attribute__((ext_vector_type(2)));
typedef unsigned int   u32x4 __attribute__((ext_vector_type(4)));
typedef unsigned short us8   __attribute__((ext_vector_type(8)));
typedef unsigned short us4   __attribute__((ext_vector_type(4)));

__device__ __forceinline__ float bf2f(unsigned short u) {
    union { unsigned int i; float f; } x; x.i = ((unsigned int)u) << 16; return x.f;
}
__device__ __forceinline__ unsigned short f2bf(float f) {
    union { float f; unsigned int i; } x; x.f = f;
    unsigned int r = x.i + 0x7FFFu + ((x.i >> 16) & 1u);   // RNE
    return (unsigned short)(r >> 16);
}
__device__ __forceinline__ float ubf(unsigned int u, int b) {
    return (float)((u >> (8 * b)) & 255u);   // -> v_cvt_f32_ubyteN
}

// permuted G layout: col j -> byte (c<<10) | (l<<4) | (half<<3) | b
// where c=j>>10, jc=j&1023, half=jc>>9, o=jc&511, l=o>>3, b=o&7.
// Chain: lane l's 16-byte load at c*1024+l*16 covers cols {c*1024+8l..+7}
// (bytes 0-7) and {c*1024+512+8l..+7} (bytes 8-15) -> matching vector us8
// reads at 16 B/lane stride (conflict-free ds_read_b128).
__device__ __forceinline__ int permoff(int j0) {   // j0 multiple of 4
    const int c = j0 >> 10, jc = j0 & 1023;
    return (c << 10) + (((jc & 511) >> 3) << 4) + (((jc >> 9) & 1) << 3) + (jc & 7);
}

// stage fp32 vectors to LDS as bf16 (36.9 KB total), vectorized
__device__ __forceinline__ void stage_vec(const float* __restrict__ gin,
                                          const float* __restrict__ hin,
                                          unsigned short* sg, unsigned short* sh)
{
    #pragma unroll
    for (int k = 0; k < LP_ / (2 * CT); ++k) {   // 9 iters, 2 elems/thread
        const int j2 = k * CT + (int)threadIdx.x;           // pair index
        float g0 = 0.f, g1 = 0.f, h0 = 0.f, h1 = 0.f;
        if (2 * j2 < L_) {                                  // L_ even -> pair-clean
            const f32x2 gp = *(const f32x2*)(gin + 2 * j2);
            const f32x2 hp = *(const f32x2*)(hin + 2 * j2);
            g0 = gp[0]; g1 = gp[1]; h0 = hp[0]; h1 = hp[1];
        }
        *(unsigned int*)(sg + 2 * j2) = (unsigned)f2bf(g0) | ((unsigned)f2bf(g1) << 16);
        *(unsigned int*)(sh + 2 * j2) = (unsigned)f2bf(h0) | ((unsigned)f2bf(h1) << 16);
    }
    __syncthreads();
}

__device__ __forceinline__ void red_store(float ag, float ah, int lane, int row,
                                          float* __restrict__ gout, float* __restrict__ hout)
{
    #pragma unroll
    for (int o = 32; o; o >>= 1) { ag += __shfl_xor(ag, o); ah += __shfl_xor(ah, o); }
    if (lane == 0) { gout[row] = ag; hout[row] = ah; }
}

// ---------------- full-precision row FMA (hi+lo, int16 fixed point) ----------------
template<bool PF>
__device__ __forceinline__ void fma_full(const unsigned short* sg, const unsigned short* sh,
                                         int lane, u32x4 (&mh)[9], u32x4 (&ml)[9],
                                         const unsigned char* RnH, const unsigned char* RnL,
                                         float& ag, float& ah)
{
    #pragma unroll
    for (int c = 0; c < 9; ++c) {
        const u32x4 uh = mh[c], ul = ml[c];
        if constexpr (PF) {                        // prefetch next row into dead regs
            mh[c] = *(const u32x4*)(RnH + c * 1024);
            ml[c] = *(const u32x4*)(RnL + c * 1024);
        }
        const int bA = c * 1024 + lane * 8, bB = bA + 512;  // shorts; 16 B/lane stride
        const us8 vgA = *(const us8*)(sg + bA), vhA = *(const us8*)(sh + bA);
        const us8 vgB = *(const us8*)(sg + bB), vhB = *(const us8*)(sh + bB);
        #pragma unroll
        for (int d = 0; d < 4; ++d)
            #pragma unroll
            for (int b = 0; b < 4; ++b) {
                const int bb = 4 * d + b, e = bb & 7;       // compile-time
                const float v = fmaf(ubf(uh[d], b), DHI, fmaf(ubf(ul[d], b), D16, -C2));
                ag = fmaf(v, bf2f(bb < 8 ? vgA[e] : vgB[e]), ag);
                ah = fmaf(v, bf2f(bb < 8 ? vhA[e] : vhB[e]), ah);
            }
    }
}

__global__ __launch_bounds__(CT)
void chain_full(const unsigned char* __restrict__ GHi, const unsigned char* __restrict__ GLo,
                const float* __restrict__ gin, const float* __restrict__ hin,
                float* __restrict__ gout, float* __restrict__ hout)
{
    __shared__ __align__(16) unsigned short sg[LP_], sh[LP_];
    stage_vec(gin, hin, sg, sh);
    const int lane = threadIdx.x & 63;
    const int w = blockIdx.x * (CT / 64) + ((int)threadIdx.x >> 6);
    const int r1 = w, r2 = w + CWAVES;      // both < L_ by construction
    // striped extra row: bijective over the 646 remainder rows
    const int e0 = (w * CEXTRA) >> 12, e1 = ((w + 1) * CEXTRA) >> 12;  // /4096
    const bool has3 = (e1 > e0);
    const int r3 = 2 * CWAVES + e0;

    const unsigned char* R1H = GHi + (size_t)r1 * LP_ + lane * 16;
    const unsigned char* R1L = GLo + (size_t)r1 * LP_ + lane * 16;
    const unsigned char* R2H = GHi + (size_t)r2 * LP_ + lane * 16;
    const unsigned char* R2L = GLo + (size_t)r2 * LP_ + lane * 16;
    const unsigned char* R3H = GHi + (size_t)r3 * LP_ + lane * 16;
    const unsigned char* R3L = GLo + (size_t)r3 * LP_ + lane * 16;

    u32x4 mh[9], ml[9];
    #pragma unroll
    for (int c = 0; c < 9; ++c) {
        mh[c] = *(const u32x4*)(R1H + c * 1024);
        ml[c] = *(const u32x4*)(R1L + c * 1024);
    }
    float ag = 0.f, ah = 0.f;
    fma_full<true>(sg, sh, lane, mh, ml, R2H, R2L, ag, ah);   // r1, prefetch r2
    red_store(ag, ah, lane, r1, gout, hout);
    if (has3) {
        ag = 0.f; ah = 0.f;
        fma_full<true>(sg, sh, lane, mh, ml, R3H, R3L, ag, ah);  // r2, prefetch r3
        red_store(ag, ah, lane, r2, gout, hout);
        ag = 0.f; ah = 0.f;
        fma_full<false>(sg, sh, lane, mh, ml, R3H, R3L, ag, ah); // r3
        red_store(ag, ah, lane, r3, gout, hout);
    } else {
        ag = 0.f; ah = 0.f;
        fma_full<false>(sg, sh, lane, mh, ml, R2H, R2L, ag, ah); // r2
        red_store(ag, ah, lane, r2, gout, hout);
    }
}

// ---------------- hi-only row FMA (int8, 81 MB/pass) ----------------
template<bool PF>
__device__ __forceinline__ void fma_hi(const unsigned short* sg, const unsigned short* sh,
                                       int lane, u32x4 (&mh)[9],
                                       const unsigned char* RnH,
                                       float& ag, float& ah)
{
    #pragma unroll
    for (int c = 0; c < 9; ++c) {
        const u32x4 uh = mh[c];
        if constexpr (PF) mh[c] = *(const u32x4*)(RnH + c * 1024);
        const int bA = c * 1024 + lane * 8, bB = bA + 512;
        const us8 vgA = *(const us8*)(sg + bA), vhA = *(const us8*)(sh + bA);
        const us8 vgB = *(const us8*)(sg + bB), vhB = *(const us8*)(sh + bB);
        #pragma unroll
        for (int d = 0; d < 4; ++d)
            #pragma unroll
            for (int b = 0; b < 4; ++b) {
                const int bb = 4 * d + b, e = bb & 7;
                const float v = fmaf(ubf(uh[d], b), DHI, -BOFF);
                ag = fmaf(v, bf2f(bb < 8 ? vgA[e] : vgB[e]), ag);
                ah = fmaf(v, bf2f(bb < 8 ? vhA[e] : vhB[e]), ah);
            }
    }
}

__global__ __launch_bounds__(CT)
void chain_hi(const unsigned char* __restrict__ GHi,
              const float* __restrict__ gin, const float* __restrict__ hin,
              float* __restrict__ gout, float* __restrict__ hout)
{
    __shared__ __align__(16) unsigned short sg[LP_], sh[LP_];
    stage_vec(gin, hin, sg, sh);
    const int lane = threadIdx.x & 63;
    const int w = blockIdx.x * (CT / 64) + ((int)threadIdx.x >> 6);
    const int r1 = w, r2 = w + CWAVES;
    const int e0 = (w * CEXTRA) >> 12, e1 = ((w + 1) * CEXTRA) >> 12;
    const bool has3 = (e1 > e0);
    const int r3 = 2 * CWAVES + e0;

    const unsigned char* R1H = GHi + (size_t)r1 * LP_ + lane * 16;
    const unsigned char* R2H = GHi + (size_t)r2 * LP_ + lane * 16;
    const unsigned char* R3H = GHi + (size_t)r3 * LP_ + lane * 16;

    u32x4 mh[9];
    #pragma unroll
    for (int c = 0; c < 9; ++c) mh[c] = *(const u32x4*)(R1H + c * 1024);
    float ag = 0.f, ah = 0.f;
    fma_hi<true>(sg, sh, lane, mh, R2H, ag, ah);
    red_store(ag, ah, lane, r1, gout, hout);
    if (has3) {
        ag = 0.f; ah = 0.f;
        fma_hi<true>(sg, sh, lane, mh, R3H, ag, ah);
        red_store(ag, ah, lane, r2, gout, hout);
        ag = 0.f; ah = 0.f;
        fma_hi<false>(sg, sh, lane, mh, R3H, ag, ah);
        red_store(ag, ah, lane, r3, gout, hout);
    } else {
        ag = 0.f; ah = 0.f;
        fma_hi<false>(sg, sh, lane, mh, R2H, ag, ah);
        red_store(ag, ah, lane, r2, gout, hout);
    }
}

// ---------------- pass 0: fp32 A, exact (A-I)*v, fused permuted hi/lo write ----------------
__device__ __forceinline__ void quant4(const float x[4], int j0, int rdiag,
                                       unsigned int& hw, unsigned int& lw)
{
    hw = 0; lw = 0;
    #pragma unroll
    for (int e = 0; e < 4; ++e) {
        const float g = x[e] - ((j0 + e == rdiag) ? 1.f : 0.f);
        int q = __float2int_rn(fmaf(g, QS, 32768.0f));
        q = min(max(q, 0), 65535);
        const int h = min((q + 128) >> 8, 255);
        const int l = min(q - (h << 8) + 128, 255);
        hw |= (unsigned)h << (8 * e);
        lw |= (unsigned)l << (8 * e);
    }
}

template<bool WRITE_G>
__device__ __forceinline__ void p0_row(const float* __restrict__ Arow,
                                       unsigned char* __restrict__ WH,
                                       unsigned char* __restrict__ WL,
                                       int row, const unsigned short* sg,
                                       const unsigned short* sh, int lane,
                                       float* __restrict__ gout, float* __restrict__ hout)
{
    float ag = 0.f, ah = 0.f;
    f32x4 buf[P0DEPTH];
    #pragma unroll
    for (int i = 0; i < P0DEPTH; ++i)
        buf[i] = __builtin_nontemporal_load((const f32x4*)(Arow + i * 256 + lane * 4));

    #pragma unroll   // full unroll: ring index stays compile-time (no scratch)
    for (int it = 0; it < 34; ++it) {        // cols 0..8703
        const int j0 = it * 256 + lane * 4;
        const f32x4 x = buf[it % P0DEPTH];
        if (it + P0DEPTH < 34)
            buf[it % P0DEPTH] = __builtin_nontemporal_load(
                (const f32x4*)(Arow + (it + P0DEPTH) * 256 + lane * 4));
        if constexpr (WRITE_G) {
            float y[4] = {x[0], x[1], x[2], x[3]};
            unsigned int hw, lw;
            quant4(y, j0, row, hw, lw);
            const int po = permoff(j0);
            *(unsigned int*)(WH + po) = hw;
            *(unsigned int*)(WL + po) = lw;
        }
        const us4 vg = *(const us4*)(sg + j0);   // 8 B/lane, conflict-free
        const us4 vh = *(const us4*)(sh + j0);
        #pragma unroll
        for (int e = 0; e < 4; ++e) {
            ag = fmaf(x[e], bf2f(vg[e]), ag);
            ah = fmaf(x[e], bf2f(vh[e]), ah);
        }
    }
    {   // tail (cols 8704..8959, guarded; OOB quantizes exact zero)
        const int j0 = 34 * 256 + lane * 4;
        float x[4];
        #pragma unroll
        for (int e = 0; e < 4; ++e) x[e] = (j0 + e < L_) ? Arow[j0 + e] : 0.f;
        if constexpr (WRITE_G) {
            unsigned int hw, lw;
            quant4(x, j0, row, hw, lw);
            const int po = permoff(j0);
            *(unsigned int*)(WH + po) = hw;
            *(unsigned int*)(WL + po) = lw;
        }
        const us4 vg = *(const us4*)(sg + j0);   // zeros beyond L_
        const us4 vh = *(const us4*)(sh + j0);
        #pragma unroll
        for (int e = 0; e < 4; ++e) {
            ag = fmaf(x[e], bf2f(vg[e]), ag);
            ah = fmaf(x[e], bf2f(vh[e]), ah);
        }
    }
    // cols 8960..9215 of WH/WL stay unwritten: they multiply zero vector entries.
    #pragma unroll
    for (int o = 32; o; o >>= 1) { ag += __shfl_xor(ag, o); ah += __shfl_xor(ah, o); }
    if (lane == 0) {   // subtract the SAME rounded v[row] -> exact identity cancel
        gout[row] = ag - bf2f(sg[row]);
        hout[row] = ah - bf2f(sh[row]);
    }
}

template<bool WRITE_G>
__global__ __launch_bounds__(CT)
void pass0_kernel(const float* __restrict__ A,
                  const float* __restrict__ gin, const float* __restrict__ hin,
                  unsigned char* __restrict__ GHi, unsigned char* __restrict__ GLo,
                  float* __restrict__ gout, float* __restrict__ hout)
{
    __shared__ __align__(16) unsigned short sg[LP_], sh[LP_];
    stage_vec(gin, hin, sg, sh);
    const int lane = threadIdx.x & 63;
    const int w = blockIdx.x * (CT / 64) + ((int)threadIdx.x >> 6);   // < 8192

    p0_row<WRITE_G>(A + (size_t)w * L_, GHi + (size_t)w * LP_, GLo + (size_t)w * LP_,
                    w, sg, sh, lane, gout, hout);
    const int e0 = (w * P0EXTRA) >> 13, e1 = ((w + 1) * P0EXTRA) >> 13;  // /8192
    if (e1 > e0) {
        const int r = P0WAVES + e0;
        p0_row<WRITE_G>(A + (size_t)r * L_, GHi + (size_t)r * LP_, GLo + (size_t)r * LP_,
                        r, sg, sh, lane, gout, hout);
    }
}

// ---------------- binomial coefficients (fp64) ----------------
__global__ void coeff_kernel(const float* __restrict__ xs,
                             double* __restrict__ s, double* __restrict__ c256)
{
    const int lane = threadIdx.x;        // 64 threads
    const int t0 = lane * 4;
    float xl[8][4];
    #pragma unroll
    for (int b = 0; b < 8; ++b)
        #pragma unroll
        for (int i = 0; i < 4; ++i)
            xl[b][i] = xs[b * 256 + t0 + i];

    double c[4] = {1.0, 1.0, 1.0, 1.0};  // C(255-t, m), m starts at 0
    for (int m = 0; m <= MPOW; ++m) {
        #pragma unroll
        for (int b = 0; b < 8; ++b) {
            double part = c[0] * xl[b][0] + c[1] * xl[b][1]
                        + c[2] * xl[b][2] + c[3] * xl[b][3];
            for (int o = 32; o; o >>= 1) part += __shfl_xor(part, o);
            if (lane == 0) s[m * 8 + b] = part;
        }
        #pragma unroll
        for (int i = 0; i < 4; ++i) {
            double k = (double)(255 - (t0 + i));
            c[i] *= (k - m) / (double)(m + 1);   // -> C(k, m+1); 0 past m=k
        }
    }
    if (lane == 0) {
        double c2 = 1.0;
        for (int m = 0; m <= MPOW; ++m) { c256[m] = c2; c2 = c2 * (256.0 - m) / (double)(m + 1); }
    }
}

// ---------------- combine: p_final[b,i] ----------------
__global__ __launch_bounds__(256)
void combine_kernel(const float* __restrict__ gv, const float* __restrict__ hv,
                    const double* __restrict__ s, const double* __restrict__ c256,
                    float* __restrict__ pfin)
{
    int i = blockIdx.x * 256 + threadIdx.x;
    if (i >= L_) return;
    double acc[8] = {0, 0, 0, 0, 0, 0, 0, 0};
    double hs = 0.0;
    for (int m = 0; m <= MPOW; ++m) {
        double g = (double)gv[(size_t)m * L_ + i];
        double h = (double)hv[(size_t)m * L_ + i];
        hs += c256[m] * h;
        #pragma unroll
        for (int b = 0; b < 8; ++b) acc[b] += s[m * 8 + b] * g;
    }
    #pragma unroll
    for (int b = 0; b < 8; ++b)
        pfin[(size_t)b * L_ + i] = (float)(acc[b] + hs);
}

// ---------------- MLP evaluation ----------------
// weights p: W1[0:64] b1[64:128] W2[128:4224] b2[4224:4288]
//            W3[4288:8384] b3[8384:8448] W4[8448:8832] b4[8832:8838]
__global__ __launch_bounds__(64)
void mlp_kernel(const float* __restrict__ pfin, const float* __restrict__ ts,
                float* __restrict__ out)
{
    const int b = blockIdx.x;
    const int t = blockIdx.y * 64 + threadIdx.x;
    const float* __restrict__ p = pfin + (size_t)b * L_;   // uniform -> s_loads
    const float tv = ts[b * 256 + t];

    float h1[64], h2[64];
    #pragma unroll
    for (int o = 0; o < 64; ++o)
        h1[o] = fmaxf(fmaf(p[o], tv, p[64 + o]), 0.f);
    #pragma unroll
    for (int o = 0; o < 64; ++o) {
        float a0 = p[4224 + o], a1 = 0.f, a2 = 0.f, a3 = 0.f;
        #pragma unroll
        for (int d = 0; d < 64; d += 4) {
            a0 = fmaf(p[128 + o * 64 + d + 0], h1[d + 0], a0);
            a1 = fmaf(p[128 + o * 64 + d + 1], h1[d + 1], a1);
            a2 = fmaf(p[128 + o * 64 + d + 2], h1[d + 2], a2);
            a3 = fmaf(p[128 + o * 64 + d + 3], h1[d + 3], a3);
        }
        h2[o] = fmaxf((a0 + a1) + (a2 + a3), 0.f);
    }
    #pragma unroll
    for (int o = 0; o < 64; ++o) {
        float a0 = p[8384 + o], a1 = 0.f, a2 = 0.f, a3 = 0.f;
        #pragma unroll
        for (int d = 0; d < 64; d += 4) {
            a0 = fmaf(p[4288 + o * 64 + d + 0], h2[d + 0], a0);
            a1 = fmaf(p[4288 + o * 64 + d + 1], h2[d + 1], a1);
            a2 = fmaf(p[4288 + o * 64 + d + 2], h2[d + 2], a2);
            a3 = fmaf(p[4288 + o * 64 + d + 3], h2[d + 3], a3);
        }
        h1[o] = fmaxf((a0 + a1) + (a2 + a3), 0.f);   // reuse as h3
    }
    #pragma unroll
    for (int o = 0; o < 6; ++o) {
        float a0 = p[8832 + o], a1 = 0.f, a2 = 0.f, a3 = 0.f;
        #pragma unroll
        for (int d = 0; d < 64; d += 4) {
            a0 = fmaf(p[8448 + o * 64 + d + 0], h1[d + 0], a0);
            a1 = fmaf(p[8448 + o * 64 + d + 1], h1[d + 1], a1);
            a2 = fmaf(p[8448 + o * 64 + d + 2], h1[d + 2], a2);
            a3 = fmaf(p[8448 + o * 64 + d + 3], h1[d + 3], a3);
        }
        out[((size_t)(b * 256 + t)) * 6 + o] = (a0 + a1) + (a2 + a3);
    }
}

// ---------------- host launcher ----------------
extern "C" void kernel_launch(void* const* d_in, const int* in_sizes, int n_in,
                              void* d_out, int out_size, void* d_ws, size_t ws_size,
                              hipStream_t stream)
{
    const float* xs    = (const float*)d_in[0];  // (8,1,256,1)
    const float* ts    = (const float*)d_in[1];  // (8,256)
    const float* theta = (const float*)d_in[2];  // (8838,)
    const float* A     = (const float*)d_in[3];  // (8838,8838)
    const float* B     = (const float*)d_in[4];  // (8838,1)
    float* out = (float*)d_out;

    const size_t GB1 = (size_t)L_ * LP_;                          // 81,451,008 per array
    const size_t VB  = (size_t)NSLOT * L_ * sizeof(float);
    const size_t SB  = (size_t)NSLOT * 8 * sizeof(double);
    const size_t CB  = 256;                                       // c256 (padded)
    const size_t PB  = (size_t)8 * L_ * sizeof(float);
    const size_t SMALL = 2 * VB + SB + CB + PB;
    const size_t FULL  = 2 * GB1 + SMALL;

    if (ws_size < SMALL) return;   // cannot run; fail loudly via validation
    const bool fat = (ws_size >= FULL);

    char* base = (char*)d_ws;
    unsigned char* GHi = (unsigned char*)base;
    unsigned char* GLo = (unsigned char*)(base + GB1);
    size_t off = fat ? 2 * GB1 : 0;
    float*  gv   = (float*)(base + off);  off += VB;
    float*  hv   = (float*)(base + off);  off += VB;
    double* s    = (double*)(base + off); off += SB;
    double* c256 = (double*)(base + off); off += CB;
    float*  pfin = (float*)(base + off);

    // independent of chain -> launch first
    coeff_kernel<<<1, 64, 0, stream>>>(xs, s, c256);

    // slot 0: g_0 = B, h_0 = theta (exact fp32)
    hipMemcpyAsync(gv, B,     L_ * sizeof(float), hipMemcpyDeviceToDevice, stream);
    hipMemcpyAsync(hv, theta, L_ * sizeof(float), hipMemcpyDeviceToDevice, stream);

    if (fat) {
        // pass 0: fp32 A (nt, 12-deep pipeline), exact slot1, fused permuted G write
        pass0_kernel<true><<<dim3(P0GRID), dim3(CT), 0, stream>>>(
            A, gv, hv, GHi, GLo, gv + L_, hv + L_);
        for (int p = 1; p < MPOW; ++p) {
            const float* gi = gv + (size_t)p * L_;
            const float* hi = hv + (size_t)p * L_;
            float* go = gv + (size_t)(p + 1) * L_;
            float* ho = hv + (size_t)(p + 1) * L_;
            if (p <= NFULL)
                chain_full<<<dim3(CWGRID), dim3(CT), 0, stream>>>(GHi, GLo, gi, hi, go, ho);
            else
                chain_hi<<<dim3(CWGRID), dim3(CT), 0, stream>>>(GHi, gi, hi, go, ho);
        }
    } else {
        for (int p = 0; p < MPOW; ++p)
            pass0_kernel<false><<<dim3(P0GRID), dim3(CT), 0, stream>>>(A,
                gv + (size_t)p * L_,       hv + (size_t)p * L_,
                nullptr, nullptr,
                gv + (size_t)(p + 1) * L_, hv + (size_t)(p + 1) * L_);
    }

    combine_kernel<<<(L_ + 255) / 256, 256, 0, stream>>>(gv, hv, s, c256, pfin);
    mlp_kernel<<<dim3(8, 4), 64, 0, stream>>>(pfin, ts, out);
}

// Round 9
// 433.608 us; speedup vs baseline: 3.6101x; 3.6101x over previous
//
#include <hip/hip_runtime.h>

// ---------------- problem constants ----------------
#define L_      8838           // LATENT
#define LP_     9216           // padded row length (u8 bytes per G row; bf16 per LDS vec)
#define MPOW    8              // highest kept power of G
#define NSLOT   (MPOW + 1)
#define NFULL   2              // passes 1..NFULL read hi+lo; later passes hi-only
#define CT      512            // threads per block (8 waves)
#define CWGRID  512            // chain grid (grid-stride over rows)
#define CWAVES  (CWGRID * (CT / 64))   // 4096
#define P0BLK   ((L_ + 7) / 8)         // 1105 blocks, one row per wave
#define P0DEPTH 12                     // pass0 load pipeline depth (16B each)

// quantization: q16 = clamp(rn((g + BOFF)/D16), 0, 65535), g = q16*D16 - BOFF
// hi = rn(q16/256) (unbiased hi-only recon), lo = q16 - 256*hi + 128
#define BOFF 6.0e-4f
#define D16  (BOFF / 32768.0f)
#define DHI  (BOFF / 128.0f)           // 256 * D16 ; exact zero recon for pad cols
#define C2   (BOFF + 128.0f * D16)
#define QS   (32768.0f / BOFF)

typedef float          f32x4 __attribute__((ext_vector_type(4)));
typedef float          f32x2 __attribute__((ext_vector_type(2)));
typedef unsigned int   u32x2 __attribute__((ext_vector_type(2)));
typedef unsigned short us8   __attribute__((ext_vector_type(8)));
typedef unsigned short us4   __attribute__((ext_vector_type(4)));

__device__ __forceinline__ float bf2f(unsigned short u) {
    union { unsigned int i; float f; } x; x.i = ((unsigned int)u) << 16; return x.f;
}
__device__ __forceinline__ unsigned short f2bf(float f) {
    union { float f; unsigned int i; } x; x.f = f;
    unsigned int r = x.i + 0x7FFFu + ((x.i >> 16) & 1u);   // RNE
    return (unsigned short)(r >> 16);
}
__device__ __forceinline__ float ubf(unsigned int u, int b) {
    return (float)((u >> (8 * b)) & 255u);   // -> v_cvt_f32_ubyteN
}

// stage fp32 vectors to LDS as bf16 (36.9 KB total), vectorized.
// NATURAL column order. Chain reads: lane l, chunk c -> shorts c*512+8l..+7
// = one us8 at 16 B/lane stride -> conflict-free ds_read_b128.
__device__ __forceinline__ void stage_vec(const float* __restrict__ gin,
                                          const float* __restrict__ hin,
                                          unsigned short* sg, unsigned short* sh)
{
    #pragma unroll
    for (int k = 0; k < LP_ / (2 * CT); ++k) {   // 9 iters, 2 elems/thread
        const int j2 = k * CT + (int)threadIdx.x;           // pair index
        float g0 = 0.f, g1 = 0.f, h0 = 0.f, h1 = 0.f;
        if (2 * j2 < L_) {                                  // L_ even -> pair-clean
            const f32x2 gp = *(const f32x2*)(gin + 2 * j2);
            const f32x2 hp = *(const f32x2*)(hin + 2 * j2);
            g0 = gp[0]; g1 = gp[1]; h0 = hp[0]; h1 = hp[1];
        }
        *(unsigned int*)(sg + 2 * j2) = (unsigned)f2bf(g0) | ((unsigned)f2bf(g1) << 16);
        *(unsigned int*)(sh + 2 * j2) = (unsigned)f2bf(h0) | ((unsigned)f2bf(h1) << 16);
    }
    __syncthreads();
}

__device__ __forceinline__ void red_store(float ag, float ah, int lane, int row,
                                          float* __restrict__ gout, float* __restrict__ hout)
{
    #pragma unroll
    for (int o = 32; o; o >>= 1) { ag += __shfl_xor(ag, o); ah += __shfl_xor(ah, o); }
    if (lane == 0) { gout[row] = ag; hout[row] = ah; }
}

// ---------------- full-precision row FMA (hi+lo, int16 fixed point) ----------------
// 18 chunks x 8 B/lane G loads (natural layout); vector us8 at 16 B/lane stride.
template<bool PF>
__device__ __forceinline__ void fma_full(const unsigned short* sg, const unsigned short* sh,
                                         int lane, u32x2 (&mh)[18], u32x2 (&ml)[18],
                                         const unsigned char* RnH, const unsigned char* RnL,
                                         float& ag, float& ah)
{
    #pragma unroll
    for (int c = 0; c < 18; ++c) {
        const u32x2 uh = mh[c], ul = ml[c];
        if constexpr (PF) {                        // prefetch next row into dead regs
            mh[c] = *(const u32x2*)(RnH + c * 512);
            ml[c] = *(const u32x2*)(RnL + c * 512);
        }
        const int jb = c * 512 + lane * 8;         // short index; 16 B/lane
        const us8 vg = *(const us8*)(sg + jb);
        const us8 vh = *(const us8*)(sh + jb);
        #pragma unroll
        for (int d = 0; d < 2; ++d)
            #pragma unroll
            for (int b = 0; b < 4; ++b) {
                const int e = 4 * d + b;           // compile-time
                const float v = fmaf(ubf(uh[d], b), DHI, fmaf(ubf(ul[d], b), D16, -C2));
                ag = fmaf(v, bf2f(vg[e]), ag);
                ah = fmaf(v, bf2f(vh[e]), ah);
            }
    }
}

__global__ __launch_bounds__(CT)
void chain_full(const unsigned char* __restrict__ GHi, const unsigned char* __restrict__ GLo,
                const float* __restrict__ gin, const float* __restrict__ hin,
                float* __restrict__ gout, float* __restrict__ hout)
{
    __shared__ __align__(16) unsigned short sg[LP_], sh[LP_];
    stage_vec(gin, hin, sg, sh);
    const int lane = threadIdx.x & 63;
    int row = blockIdx.x * (CT / 64) + ((int)threadIdx.x >> 6);

    u32x2 mh[18], ml[18];
    if (row < L_) {
        const unsigned char* RH = GHi + (size_t)row * LP_ + lane * 8;
        const unsigned char* RL = GLo + (size_t)row * LP_ + lane * 8;
        #pragma unroll
        for (int c = 0; c < 18; ++c) {
            mh[c] = *(const u32x2*)(RH + c * 512);
            ml[c] = *(const u32x2*)(RL + c * 512);
        }
    }
    while (row < L_) {
        const int nrow = row + CWAVES;
        const unsigned char* RnH = GHi + (size_t)nrow * LP_ + lane * 8;
        const unsigned char* RnL = GLo + (size_t)nrow * LP_ + lane * 8;
        float ag = 0.f, ah = 0.f;
        if (nrow < L_) fma_full<true >(sg, sh, lane, mh, ml, RnH, RnL, ag, ah);
        else           fma_full<false>(sg, sh, lane, mh, ml, RnH, RnL, ag, ah);
        red_store(ag, ah, lane, row, gout, hout);
        row = nrow;
    }
}

// ---------------- hi-only row FMA (int8, 81 MB/pass) ----------------
template<bool PF>
__device__ __forceinline__ void fma_hi(const unsigned short* sg, const unsigned short* sh,
                                       int lane, u32x2 (&mh)[18],
                                       const unsigned char* RnH,
                                       float& ag, float& ah)
{
    #pragma unroll
    for (int c = 0; c < 18; ++c) {
        const u32x2 uh = mh[c];
        if constexpr (PF) mh[c] = *(const u32x2*)(RnH + c * 512);
        const int jb = c * 512 + lane * 8;
        const us8 vg = *(const us8*)(sg + jb);
        const us8 vh = *(const us8*)(sh + jb);
        #pragma unroll
        for (int d = 0; d < 2; ++d)
            #pragma unroll
            for (int b = 0; b < 4; ++b) {
                const int e = 4 * d + b;
                const float v = fmaf(ubf(uh[d], b), DHI, -BOFF);
                ag = fmaf(v, bf2f(vg[e]), ag);
                ah = fmaf(v, bf2f(vh[e]), ah);
            }
    }
}

__global__ __launch_bounds__(CT)
void chain_hi(const unsigned char* __restrict__ GHi,
              const float* __restrict__ gin, const float* __restrict__ hin,
              float* __restrict__ gout, float* __restrict__ hout)
{
    __shared__ __align__(16) unsigned short sg[LP_], sh[LP_];
    stage_vec(gin, hin, sg, sh);
    const int lane = threadIdx.x & 63;
    int row = blockIdx.x * (CT / 64) + ((int)threadIdx.x >> 6);

    u32x2 mh[18];
    if (row < L_) {
        const unsigned char* RH = GHi + (size_t)row * LP_ + lane * 8;
        #pragma unroll
        for (int c = 0; c < 18; ++c) mh[c] = *(const u32x2*)(RH + c * 512);
    }
    while (row < L_) {
        const int nrow = row + CWAVES;
        const unsigned char* RnH = GHi + (size_t)nrow * LP_ + lane * 8;
        float ag = 0.f, ah = 0.f;
        if (nrow < L_) fma_hi<true >(sg, sh, lane, mh, RnH, ag, ah);
        else           fma_hi<false>(sg, sh, lane, mh, RnH, ag, ah);
        red_store(ag, ah, lane, row, gout, hout);
        row = nrow;
    }
}

// ---------------- pass 0: fp32 A, exact (A-I)*v, fused NATURAL hi/lo write ----------------
__device__ __forceinline__ void quant4(const float x[4], int j0, int rdiag,
                                       unsigned int& hw, unsigned int& lw)
{
    hw = 0; lw = 0;
    #pragma unroll
    for (int e = 0; e < 4; ++e) {
        const float g = x[e] - ((j0 + e == rdiag) ? 1.f : 0.f);
        int q = __float2int_rn(fmaf(g, QS, 32768.0f));
        q = min(max(q, 0), 65535);
        const int h = min((q + 128) >> 8, 255);
        const int l = min(q - (h << 8) + 128, 255);
        hw |= (unsigned)h << (8 * e);
        lw |= (unsigned)l << (8 * e);
    }
}

template<bool WRITE_G>
__global__ __launch_bounds__(CT)
void pass0_kernel(const float* __restrict__ A,
                  const float* __restrict__ gin, const float* __restrict__ hin,
                  unsigned char* __restrict__ GHi, unsigned char* __restrict__ GLo,
                  float* __restrict__ gout, float* __restrict__ hout)
{
    __shared__ __align__(16) unsigned short sg[LP_], sh[LP_];
    stage_vec(gin, hin, sg, sh);
    const int lane = threadIdx.x & 63;
    const int row = blockIdx.x * (CT / 64) + ((int)threadIdx.x >> 6);
    if (row >= L_) return;
    const float* __restrict__ Arow = A + (size_t)row * L_;
    unsigned char* __restrict__ WH = GHi + (size_t)row * LP_;
    unsigned char* __restrict__ WL = GLo + (size_t)row * LP_;

    float ag = 0.f, ah = 0.f;
    f32x4 buf[P0DEPTH];
    #pragma unroll
    for (int i = 0; i < P0DEPTH; ++i)
        buf[i] = __builtin_nontemporal_load((const f32x4*)(Arow + i * 256 + lane * 4));

    #pragma unroll   // full unroll: ring index stays compile-time (no scratch)
    for (int it = 0; it < 34; ++it) {        // cols 0..8703
        const int j0 = it * 256 + lane * 4;
        const f32x4 x = buf[it % P0DEPTH];
        if (it + P0DEPTH < 34)
            buf[it % P0DEPTH] = __builtin_nontemporal_load(
                (const f32x4*)(Arow + (it + P0DEPTH) * 256 + lane * 4));
        if constexpr (WRITE_G) {
            float y[4] = {x[0], x[1], x[2], x[3]};
            unsigned int hw, lw;
            quant4(y, j0, row, hw, lw);
            *(unsigned int*)(WH + j0) = hw;   // natural order, coalesced 4B/lane
            *(unsigned int*)(WL + j0) = lw;
        }
        const us4 vg = *(const us4*)(sg + j0);   // 8 B/lane, conflict-free
        const us4 vh = *(const us4*)(sh + j0);
        #pragma unroll
        for (int e = 0; e < 4; ++e) {
            ag = fmaf(x[e], bf2f(vg[e]), ag);
            ah = fmaf(x[e], bf2f(vh[e]), ah);
        }
    }
    {   // tail (cols 8704..8959, guarded; OOB quantizes exact zero)
        const int j0 = 34 * 256 + lane * 4;
        float x[4];
        #pragma unroll
        for (int e = 0; e < 4; ++e) x[e] = (j0 + e < L_) ? Arow[j0 + e] : 0.f;
        if constexpr (WRITE_G) {
            unsigned int hw, lw;
            quant4(x, j0, row, hw, lw);
            *(unsigned int*)(WH + j0) = hw;
            *(unsigned int*)(WL + j0) = lw;
        }
        const us4 vg = *(const us4*)(sg + j0);   // zeros beyond L_
        const us4 vh = *(const us4*)(sh + j0);
        #pragma unroll
        for (int e = 0; e < 4; ++e) {
            ag = fmaf(x[e], bf2f(vg[e]), ag);
            ah = fmaf(x[e], bf2f(vh[e]), ah);
        }
    }
    // cols 8960..9215 of WH/WL stay unwritten: they multiply zero vector entries.
    #pragma unroll
    for (int o = 32; o; o >>= 1) { ag += __shfl_xor(ag, o); ah += __shfl_xor(ah, o); }
    if (lane == 0) {   // subtract the SAME rounded v[row] -> exact identity cancel
        gout[row] = ag - bf2f(sg[row]);
        hout[row] = ah - bf2f(sh[row]);
    }
}

// ---------------- binomial coefficients (fp64) ----------------
__global__ void coeff_kernel(const float* __restrict__ xs,
                             double* __restrict__ s, double* __restrict__ c256)
{
    const int lane = threadIdx.x;        // 64 threads
    const int t0 = lane * 4;
    float xl[8][4];
    #pragma unroll
    for (int b = 0; b < 8; ++b)
        #pragma unroll
        for (int i = 0; i < 4; ++i)
            xl[b][i] = xs[b * 256 + t0 + i];

    double c[4] = {1.0, 1.0, 1.0, 1.0};  // C(255-t, m), m starts at 0
    for (int m = 0; m <= MPOW; ++m) {
        #pragma unroll
        for (int b = 0; b < 8; ++b) {
            double part = c[0] * xl[b][0] + c[1] * xl[b][1]
                        + c[2] * xl[b][2] + c[3] * xl[b][3];
            for (int o = 32; o; o >>= 1) part += __shfl_xor(part, o);
            if (lane == 0) s[m * 8 + b] = part;
        }
        #pragma unroll
        for (int i = 0; i < 4; ++i) {
            double k = (double)(255 - (t0 + i));
            c[i] *= (k - m) / (double)(m + 1);   // -> C(k, m+1); 0 past m=k
        }
    }
    if (lane == 0) {
        double c2 = 1.0;
        for (int m = 0; m <= MPOW; ++m) { c256[m] = c2; c2 = c2 * (256.0 - m) / (double)(m + 1); }
    }
}

// ---------------- combine: p_final[b,i] ----------------
__global__ __launch_bounds__(256)
void combine_kernel(const float* __restrict__ gv, const float* __restrict__ hv,
                    const double* __restrict__ s, const double* __restrict__ c256,
                    float* __restrict__ pfin)
{
    int i = blockIdx.x * 256 + threadIdx.x;
    if (i >= L_) return;
    double acc[8] = {0, 0, 0, 0, 0, 0, 0, 0};
    double hs = 0.0;
    for (int m = 0; m <= MPOW; ++m) {
        double g = (double)gv[(size_t)m * L_ + i];
        double h = (double)hv[(size_t)m * L_ + i];
        hs += c256[m] * h;
        #pragma unroll
        for (int b = 0; b < 8; ++b) acc[b] += s[m * 8 + b] * g;
    }
    #pragma unroll
    for (int b = 0; b < 8; ++b)
        pfin[(size_t)b * L_ + i] = (float)(acc[b] + hs);
}

// ---------------- MLP evaluation ----------------
// weights p: W1[0:64] b1[64:128] W2[128:4224] b2[4224:4288]
//            W3[4288:8384] b3[8384:8448] W4[8448:8832] b4[8832:8838]
__global__ __launch_bounds__(64)
void mlp_kernel(const float* __restrict__ pfin, const float* __restrict__ ts,
                float* __restrict__ out)
{
    const int b = blockIdx.x;
    const int t = blockIdx.y * 64 + threadIdx.x;
    const float* __restrict__ p = pfin + (size_t)b * L_;   // uniform -> s_loads
    const float tv = ts[b * 256 + t];

    float h1[64], h2[64];
    #pragma unroll
    for (int o = 0; o < 64; ++o)
        h1[o] = fmaxf(fmaf(p[o], tv, p[64 + o]), 0.f);
    #pragma unroll
    for (int o = 0; o < 64; ++o) {
        float a0 = p[4224 + o], a1 = 0.f, a2 = 0.f, a3 = 0.f;
        #pragma unroll
        for (int d = 0; d < 64; d += 4) {
            a0 = fmaf(p[128 + o * 64 + d + 0], h1[d + 0], a0);
            a1 = fmaf(p[128 + o * 64 + d + 1], h1[d + 1], a1);
            a2 = fmaf(p[128 + o * 64 + d + 2], h1[d + 2], a2);
            a3 = fmaf(p[128 + o * 64 + d + 3], h1[d + 3], a3);
        }
        h2[o] = fmaxf((a0 + a1) + (a2 + a3), 0.f);
    }
    #pragma unroll
    for (int o = 0; o < 64; ++o) {
        float a0 = p[8384 + o], a1 = 0.f, a2 = 0.f, a3 = 0.f;
        #pragma unroll
        for (int d = 0; d < 64; d += 4) {
            a0 = fmaf(p[4288 + o * 64 + d + 0], h2[d + 0], a0);
            a1 = fmaf(p[4288 + o * 64 + d + 1], h2[d + 1], a1);
            a2 = fmaf(p[4288 + o * 64 + d + 2], h2[d + 2], a2);
            a3 = fmaf(p[4288 + o * 64 + d + 3], h2[d + 3], a3);
        }
        h1[o] = fmaxf((a0 + a1) + (a2 + a3), 0.f);   // reuse as h3
    }
    #pragma unroll
    for (int o = 0; o < 6; ++o) {
        float a0 = p[8832 + o], a1 = 0.f, a2 = 0.f, a3 = 0.f;
        #pragma unroll
        for (int d = 0; d < 64; d += 4) {
            a0 = fmaf(p[8448 + o * 64 + d + 0], h1[d + 0], a0);
            a1 = fmaf(p[8448 + o * 64 + d + 1], h1[d + 1], a1);
            a2 = fmaf(p[8448 + o * 64 + d + 2], h1[d + 2], a2);
            a3 = fmaf(p[8448 + o * 64 + d + 3], h1[d + 3], a3);
        }
        out[((size_t)(b * 256 + t)) * 6 + o] = (a0 + a1) + (a2 + a3);
    }
}

// ---------------- host launcher ----------------
extern "C" void kernel_launch(void* const* d_in, const int* in_sizes, int n_in,
                              void* d_out, int out_size, void* d_ws, size_t ws_size,
                              hipStream_t stream)
{
    const float* xs    = (const float*)d_in[0];  // (8,1,256,1)
    const float* ts    = (const float*)d_in[1];  // (8,256)
    const float* theta = (const float*)d_in[2];  // (8838,)
    const float* A     = (const float*)d_in[3];  // (8838,8838)
    const float* B     = (const float*)d_in[4];  // (8838,1)
    float* out = (float*)d_out;

    const size_t GB1 = (size_t)L_ * LP_;                          // 81,451,008 per array
    const size_t VB  = (size_t)NSLOT * L_ * sizeof(float);
    const size_t SB  = (size_t)NSLOT * 8 * sizeof(double);
    const size_t CB  = 256;                                       // c256 (padded)
    const size_t PB  = (size_t)8 * L_ * sizeof(float);
    const size_t SMALL = 2 * VB + SB + CB + PB;
    const size_t FULL  = 2 * GB1 + SMALL;

    if (ws_size < SMALL) return;   // cannot run; fail loudly via validation
    const bool fat = (ws_size >= FULL);

    char* base = (char*)d_ws;
    unsigned char* GHi = (unsigned char*)base;
    unsigned char* GLo = (unsigned char*)(base + GB1);
    size_t off = fat ? 2 * GB1 : 0;
    float*  gv   = (float*)(base + off);  off += VB;
    float*  hv   = (float*)(base + off);  off += VB;
    double* s    = (double*)(base + off); off += SB;
    double* c256 = (double*)(base + off); off += CB;
    float*  pfin = (float*)(base + off);

    // independent of chain -> launch first
    coeff_kernel<<<1, 64, 0, stream>>>(xs, s, c256);

    // slot 0: g_0 = B, h_0 = theta (exact fp32)
    hipMemcpyAsync(gv, B,     L_ * sizeof(float), hipMemcpyDeviceToDevice, stream);
    hipMemcpyAsync(hv, theta, L_ * sizeof(float), hipMemcpyDeviceToDevice, stream);

    if (fat) {
        // pass 0: fp32 A (nt, 12-deep pipeline), exact slot1, fused natural G write
        pass0_kernel<true><<<dim3(P0BLK), dim3(CT), 0, stream>>>(
            A, gv, hv, GHi, GLo, gv + L_, hv + L_);
        for (int p = 1; p < MPOW; ++p) {
            const float* gi = gv + (size_t)p * L_;
            const float* hi = hv + (size_t)p * L_;
            float* go = gv + (size_t)(p + 1) * L_;
            float* ho = hv + (size_t)(p + 1) * L_;
            if (p <= NFULL)
                chain_full<<<dim3(CWGRID), dim3(CT), 0, stream>>>(GHi, GLo, gi, hi, go, ho);
            else
                chain_hi<<<dim3(CWGRID), dim3(CT), 0, stream>>>(GHi, gi, hi, go, ho);
        }
    } else {
        for (int p = 0; p < MPOW; ++p)
            pass0_kernel<false><<<dim3(P0BLK), dim3(CT), 0, stream>>>(A,
                gv + (size_t)p * L_,       hv + (size_t)p * L_,
                nullptr, nullptr,
                gv + (size_t)(p + 1) * L_, hv + (size_t)(p + 1) * L_);
    }

    combine_kernel<<<(L_ + 255) / 256, 256, 0, stream>>>(gv, hv, s, c256, pfin);
    mlp_kernel<<<dim3(8, 4), 64, 0, stream>>>(pfin, ts, out);
}

// Round 10
// 407.328 us; speedup vs baseline: 3.8430x; 1.0645x over previous
//
#include <hip/hip_runtime.h>

// ---------------- problem constants ----------------
#define L_      8838           // LATENT
#define LP_     9216           // padded row length (u8 bytes per G row; f32 per LDS vec)
#define MPOW    8              // highest kept power of G
#define NSLOT   (MPOW + 1)
#define NFULL   3              // chain passes p=0..NFULL-1 read hi+lo; later hi-only
#define CT      512            // threads per block (8 waves)
#define CWGRID  512            // chain grid (grid-stride over rows), 2 blocks/CU
#define CWAVES  (CWGRID * (CT / 64))   // 4096
#define TBLK    ((L_ + 7) / 8)         // transcode: 1105 blocks, one row per wave
#define TDEPTH  12                     // transcode load pipeline depth (16B each)

// quantization: q16 = clamp(rn((g + BOFF)/D16), 0, 65535), g = q16*D16 - BOFF
// hi = rn(q16/256) (unbiased hi-only recon), lo = q16 - 256*hi + 128
#define BOFF 6.0e-4f
#define D16  (BOFF / 32768.0f)
#define DHI  (BOFF / 128.0f)           // 256 * D16 ; BOFF == 128*DHI exactly
#define C2   (BOFF + 128.0f * D16)
#define QS   (32768.0f / BOFF)

typedef float        f32x4 __attribute__((ext_vector_type(4)));
typedef float        f32x2 __attribute__((ext_vector_type(2)));

__device__ __forceinline__ float ubf(unsigned int u, int b) {
    return (float)((u >> (8 * b)) & 255u);   // -> v_cvt_f32_ubyteN (1 inst)
}
__device__ __forceinline__ f32x2 lo2(f32x4 a) { return __builtin_shufflevector(a, a, 0, 1); }
__device__ __forceinline__ f32x2 hi2(f32x4 a) { return __builtin_shufflevector(a, a, 2, 3); }
__device__ __forceinline__ f32x2 mk2(float a, float b) { f32x2 t; t.x = a; t.y = b; return t; }

// packed f32 FMA (CDNA VOP3P): d = a*b + c elementwise on 2 lanes
__device__ __forceinline__ f32x2 pk_fma3(f32x2 a, f32x2 b, f32x2 c) {
    f32x2 d;
    asm("v_pk_fma_f32 %0, %1, %2, %3" : "=v"(d) : "v"(a), "v"(b), "v"(c));
    return d;
}
__device__ __forceinline__ void pk_acc(f32x2& acc, f32x2 a, f32x2 b) {
    asm("v_pk_fma_f32 %0, %1, %2, %0" : "+v"(acc) : "v"(a), "v"(b));
}

// stage fp32 vectors to LDS (73.7 KB total -> 2 blocks/CU, grid is 2/CU anyway)
__device__ __forceinline__ void stage_vec(const float* __restrict__ gin,
                                          const float* __restrict__ hin,
                                          float* sgf, float* shf)
{
    #pragma unroll
    for (int k = 0; k < LP_ / (2 * CT); ++k) {   // 9 iters, 2 elems/thread
        const int j2 = k * CT + (int)threadIdx.x;
        float g0 = 0.f, g1 = 0.f, h0 = 0.f, h1 = 0.f;
        if (2 * j2 < L_) {                       // L_ even -> pair-clean
            const f32x2 gp = *(const f32x2*)(gin + 2 * j2);
            const f32x2 hp = *(const f32x2*)(hin + 2 * j2);
            g0 = gp.x; g1 = gp.y; h0 = hp.x; h1 = hp.y;
        }
        *(f32x2*)(sgf + 2 * j2) = mk2(g0, g1);
        *(f32x2*)(shf + 2 * j2) = mk2(h0, h1);
    }
    __syncthreads();
}

__device__ __forceinline__ void red_store(float ag, float ah, int lane, int row,
                                          float* __restrict__ gout, float* __restrict__ hout)
{
    #pragma unroll
    for (int o = 32; o; o >>= 1) { ag += __shfl_xor(ag, o); ah += __shfl_xor(ah, o); }
    if (lane == 0) { gout[row] = ag; hout[row] = ah; }
}

// ---------------- chain row FMA ----------------
// Chunk c, lane l: G words at row*LP_ + c*512 + 4l (A) and +256 (B) -> cols
// {c*512+4l..+3} and {c*512+256+4l..+3}. Matching vector reads are f32x4 at
// 16 B/lane stride (conflict-free ds_read_b128). Dequant per-element via
// packed fma (centered v ~ +-1e-4 -> same accumulation numerics as scalar).
template<bool LO, bool PF>
__device__ __forceinline__ void fma_row(const float* sgf, const float* shf, int lane,
                                        unsigned int (&mhA)[18], unsigned int (&mhB)[18],
                                        unsigned int (&mlA)[18], unsigned int (&mlB)[18],
                                        const unsigned char* RnH, const unsigned char* RnL,
                                        f32x2& accg, f32x2& acch)
{
    const f32x2 cS  = mk2(DHI, DHI);
    const f32x2 cO  = LO ? mk2(-C2, -C2) : mk2(-BOFF, -BOFF);
    const f32x2 cI  = mk2(0.00390625f, 0.00390625f);   // 1/256
    #pragma unroll
    for (int c = 0; c < 18; ++c) {
        const unsigned int hA = mhA[c], hB = mhB[c];
        unsigned int lA = 0, lB = 0;
        if constexpr (LO) { lA = mlA[c]; lB = mlB[c]; }
        if constexpr (PF) {                        // prefetch next row into dead regs
            mhA[c] = *(const unsigned int*)(RnH + c * 512);
            mhB[c] = *(const unsigned int*)(RnH + c * 512 + 256);
            if constexpr (LO) {
                mlA[c] = *(const unsigned int*)(RnL + c * 512);
                mlB[c] = *(const unsigned int*)(RnL + c * 512 + 256);
            }
        }
        const int jb = c * 512 + 4 * lane;         // float index; byte 16/lane stride
        const f32x4 vg0 = *(const f32x4*)(sgf + jb);
        const f32x4 vg1 = *(const f32x4*)(sgf + jb + 256);
        const f32x4 vh0 = *(const f32x4*)(shf + jb);
        const f32x4 vh1 = *(const f32x4*)(shf + jb + 256);

        f32x2 uA01 = mk2(ubf(hA, 0), ubf(hA, 1));
        f32x2 uA23 = mk2(ubf(hA, 2), ubf(hA, 3));
        f32x2 uB01 = mk2(ubf(hB, 0), ubf(hB, 1));
        f32x2 uB23 = mk2(ubf(hB, 2), ubf(hB, 3));
        if constexpr (LO) {                        // u += lo/256 (exact in f32)
            uA01 = pk_fma3(mk2(ubf(lA, 0), ubf(lA, 1)), cI, uA01);
            uA23 = pk_fma3(mk2(ubf(lA, 2), ubf(lA, 3)), cI, uA23);
            uB01 = pk_fma3(mk2(ubf(lB, 0), ubf(lB, 1)), cI, uB01);
            uB23 = pk_fma3(mk2(ubf(lB, 2), ubf(lB, 3)), cI, uB23);
        }
        const f32x2 vA01 = pk_fma3(uA01, cS, cO);  // centered dequant, per element
        const f32x2 vA23 = pk_fma3(uA23, cS, cO);
        const f32x2 vB01 = pk_fma3(uB01, cS, cO);
        const f32x2 vB23 = pk_fma3(uB23, cS, cO);

        pk_acc(accg, vA01, lo2(vg0)); pk_acc(accg, vA23, hi2(vg0));
        pk_acc(accg, vB01, lo2(vg1)); pk_acc(accg, vB23, hi2(vg1));
        pk_acc(acch, vA01, lo2(vh0)); pk_acc(acch, vA23, hi2(vh0));
        pk_acc(acch, vB01, lo2(vh1)); pk_acc(acch, vB23, hi2(vh1));
    }
}

template<bool LO>
__global__ __launch_bounds__(CT)
void chain_pass(const unsigned char* __restrict__ GHi, const unsigned char* __restrict__ GLo,
                const float* __restrict__ gin, const float* __restrict__ hin,
                float* __restrict__ gout, float* __restrict__ hout)
{
    __shared__ __align__(16) float sgf[LP_], shf[LP_];
    stage_vec(gin, hin, sgf, shf);
    const int lane = threadIdx.x & 63;
    int row = blockIdx.x * (CT / 64) + ((int)threadIdx.x >> 6);

    unsigned int mhA[18], mhB[18], mlA[18], mlB[18];
    if (row < L_) {
        const unsigned char* RH = GHi + (size_t)row * LP_;
        const unsigned char* RL = GLo + (size_t)row * LP_;
        #pragma unroll
        for (int c = 0; c < 18; ++c) {
            mhA[c] = *(const unsigned int*)(RH + c * 512 + 4 * lane);
            mhB[c] = *(const unsigned int*)(RH + c * 512 + 256 + 4 * lane);
            if constexpr (LO) {
                mlA[c] = *(const unsigned int*)(RL + c * 512 + 4 * lane);
                mlB[c] = *(const unsigned int*)(RL + c * 512 + 256 + 4 * lane);
            }
        }
    }
    while (row < L_) {
        const int nrow = row + CWAVES;
        const unsigned char* RnH = GHi + (size_t)nrow * LP_ + 4 * lane;
        const unsigned char* RnL = GLo + (size_t)nrow * LP_ + 4 * lane;
        f32x2 accg = mk2(0.f, 0.f), acch = mk2(0.f, 0.f);
        if (nrow < L_) fma_row<LO, true >(sgf, shf, lane, mhA, mhB, mlA, mlB, RnH, RnL, accg, acch);
        else           fma_row<LO, false>(sgf, shf, lane, mhA, mhB, mlA, mlB, RnH, RnL, accg, acch);
        red_store(accg.x + accg.y, acch.x + acch.y, lane, row, gout, hout);
        row = nrow;
    }
}

// ---------------- transcode: A (fp32, nt) -> GHi/GLo (natural layout) ----------------
__device__ __forceinline__ void quant4(const float x[4], int j0, int rdiag,
                                       unsigned int& hw, unsigned int& lw)
{
    hw = 0; lw = 0;
    #pragma unroll
    for (int e = 0; e < 4; ++e) {
        const float g = x[e] - ((j0 + e == rdiag) ? 1.f : 0.f);
        int q = __float2int_rn(fmaf(g, QS, 32768.0f));
        q = min(max(q, 0), 65535);
        const int h = min((q + 128) >> 8, 255);
        const int l = min(q - (h << 8) + 128, 255);
        hw |= (unsigned)h << (8 * e);
        lw |= (unsigned)l << (8 * e);
    }
}

__global__ __launch_bounds__(CT)
void transcode_kernel(const float* __restrict__ A,
                      unsigned char* __restrict__ GHi, unsigned char* __restrict__ GLo)
{
    const int lane = threadIdx.x & 63;
    const int row = blockIdx.x * (CT / 64) + ((int)threadIdx.x >> 6);
    if (row >= L_) return;
    const float* __restrict__ Arow = A + (size_t)row * L_;
    unsigned char* __restrict__ WH = GHi + (size_t)row * LP_;
    unsigned char* __restrict__ WL = GLo + (size_t)row * LP_;

    f32x4 buf[TDEPTH];
    #pragma unroll
    for (int i = 0; i < TDEPTH; ++i)
        buf[i] = __builtin_nontemporal_load((const f32x4*)(Arow + i * 256 + lane * 4));

    #pragma unroll   // full unroll: ring index stays compile-time (no scratch)
    for (int it = 0; it < 34; ++it) {        // cols 0..8703
        const int j0 = it * 256 + lane * 4;
        const f32x4 x = buf[it % TDEPTH];
        if (it + TDEPTH < 34)
            buf[it % TDEPTH] = __builtin_nontemporal_load(
                (const f32x4*)(Arow + (it + TDEPTH) * 256 + lane * 4));
        float y[4] = {x.x, x.y, x.z, x.w};
        unsigned int hw, lw;
        quant4(y, j0, row, hw, lw);
        *(unsigned int*)(WH + j0) = hw;      // coalesced 4B/lane
        *(unsigned int*)(WL + j0) = lw;
    }
    {   // tail (cols 8704..8959, guarded; OOB quantizes exact zero)
        const int j0 = 34 * 256 + lane * 4;
        float x[4];
        #pragma unroll
        for (int e = 0; e < 4; ++e) x[e] = (j0 + e < L_) ? Arow[j0 + e] : 0.f;
        unsigned int hw, lw;
        quant4(x, j0, row, hw, lw);
        *(unsigned int*)(WH + j0) = hw;
        *(unsigned int*)(WL + j0) = lw;
    }
    // cols 8960..9215 stay unwritten: they multiply zero vector entries.
}

// ---------------- fallback: fp32 chain directly on A (small-ws path) ----------------
__global__ __launch_bounds__(CT)
void chain_fallback(const float* __restrict__ A,
                    const float* __restrict__ gin, const float* __restrict__ hin,
                    float* __restrict__ gout, float* __restrict__ hout)
{
    __shared__ __align__(16) float sgf[LP_], shf[LP_];
    stage_vec(gin, hin, sgf, shf);
    const int lane = threadIdx.x & 63;
    int row = blockIdx.x * (CT / 64) + ((int)threadIdx.x >> 6);
    while (row < L_) {
        const float* __restrict__ Arow = A + (size_t)row * L_;
        float ag = 0.f, ah = 0.f;
        for (int it = 0; it < 36; ++it) {
            const int j0 = it * 256 + lane * 4;
            float x[4];
            if (j0 + 3 < L_) {
                const f32x4 v = *(const f32x4*)(Arow + j0);
                x[0] = v.x; x[1] = v.y; x[2] = v.z; x[3] = v.w;
            } else {
                #pragma unroll
                for (int e = 0; e < 4; ++e) x[e] = (j0 + e < L_) ? Arow[j0 + e] : 0.f;
            }
            const f32x4 vg = *(const f32x4*)(sgf + j0);
            const f32x4 vh = *(const f32x4*)(shf + j0);
            ag = fmaf(x[0], vg.x, fmaf(x[1], vg.y, fmaf(x[2], vg.z, fmaf(x[3], vg.w, ag))));
            ah = fmaf(x[0], vh.x, fmaf(x[1], vh.y, fmaf(x[2], vh.z, fmaf(x[3], vh.w, ah))));
        }
        #pragma unroll
        for (int o = 32; o; o >>= 1) { ag += __shfl_xor(ag, o); ah += __shfl_xor(ah, o); }
        if (lane == 0) {   // subtract exact identity (vectors staged fp32)
            gout[row] = ag - sgf[row];
            hout[row] = ah - shf[row];
        }
        row += CWAVES;
    }
}

// ---------------- binomial coefficients (fp64) ----------------
__global__ void coeff_kernel(const float* __restrict__ xs,
                             double* __restrict__ s, double* __restrict__ c256)
{
    const int lane = threadIdx.x;        // 64 threads
    const int t0 = lane * 4;
    float xl[8][4];
    #pragma unroll
    for (int b = 0; b < 8; ++b)
        #pragma unroll
        for (int i = 0; i < 4; ++i)
            xl[b][i] = xs[b * 256 + t0 + i];

    double c[4] = {1.0, 1.0, 1.0, 1.0};  // C(255-t, m), m starts at 0
    for (int m = 0; m <= MPOW; ++m) {
        #pragma unroll
        for (int b = 0; b < 8; ++b) {
            double part = c[0] * xl[b][0] + c[1] * xl[b][1]
                        + c[2] * xl[b][2] + c[3] * xl[b][3];
            for (int o = 32; o; o >>= 1) part += __shfl_xor(part, o);
            if (lane == 0) s[m * 8 + b] = part;
        }
        #pragma unroll
        for (int i = 0; i < 4; ++i) {
            double k = (double)(255 - (t0 + i));
            c[i] *= (k - m) / (double)(m + 1);   // -> C(k, m+1); 0 past m=k
        }
    }
    if (lane == 0) {
        double c2 = 1.0;
        for (int m = 0; m <= MPOW; ++m) { c256[m] = c2; c2 = c2 * (256.0 - m) / (double)(m + 1); }
    }
}

// ---------------- combine: p_final[b,i] ----------------
__global__ __launch_bounds__(256)
void combine_kernel(const float* __restrict__ gv, const float* __restrict__ hv,
                    const double* __restrict__ s, const double* __restrict__ c256,
                    float* __restrict__ pfin)
{
    int i = blockIdx.x * 256 + threadIdx.x;
    if (i >= L_) return;
    double acc[8] = {0, 0, 0, 0, 0, 0, 0, 0};
    double hs = 0.0;
    for (int m = 0; m <= MPOW; ++m) {
        double g = (double)gv[(size_t)m * L_ + i];
        double h = (double)hv[(size_t)m * L_ + i];
        hs += c256[m] * h;
        #pragma unroll
        for (int b = 0; b < 8; ++b) acc[b] += s[m * 8 + b] * g;
    }
    #pragma unroll
    for (int b = 0; b < 8; ++b)
        pfin[(size_t)b * L_ + i] = (float)(acc[b] + hs);
}

// ---------------- MLP evaluation ----------------
// weights p: W1[0:64] b1[64:128] W2[128:4224] b2[4224:4288]
//            W3[4288:8384] b3[8384:8448] W4[8448:8832] b4[8832:8838]
__global__ __launch_bounds__(64)
void mlp_kernel(const float* __restrict__ pfin, const float* __restrict__ ts,
                float* __restrict__ out)
{
    const int b = blockIdx.x;
    const int t = blockIdx.y * 64 + threadIdx.x;
    const float* __restrict__ p = pfin + (size_t)b * L_;   // uniform -> s_loads
    const float tv = ts[b * 256 + t];

    float h1[64], h2[64];
    #pragma unroll
    for (int o = 0; o < 64; ++o)
        h1[o] = fmaxf(fmaf(p[o], tv, p[64 + o]), 0.f);
    #pragma unroll
    for (int o = 0; o < 64; ++o) {
        float a0 = p[4224 + o], a1 = 0.f, a2 = 0.f, a3 = 0.f;
        #pragma unroll
        for (int d = 0; d < 64; d += 4) {
            a0 = fmaf(p[128 + o * 64 + d + 0], h1[d + 0], a0);
            a1 = fmaf(p[128 + o * 64 + d + 1], h1[d + 1], a1);
            a2 = fmaf(p[128 + o * 64 + d + 2], h1[d + 2], a2);
            a3 = fmaf(p[128 + o * 64 + d + 3], h1[d + 3], a3);
        }
        h2[o] = fmaxf((a0 + a1) + (a2 + a3), 0.f);
    }
    #pragma unroll
    for (int o = 0; o < 64; ++o) {
        float a0 = p[8384 + o], a1 = 0.f, a2 = 0.f, a3 = 0.f;
        #pragma unroll
        for (int d = 0; d < 64; d += 4) {
            a0 = fmaf(p[4288 + o * 64 + d + 0], h2[d + 0], a0);
            a1 = fmaf(p[4288 + o * 64 + d + 1], h2[d + 1], a1);
            a2 = fmaf(p[4288 + o * 64 + d + 2], h2[d + 2], a2);
            a3 = fmaf(p[4288 + o * 64 + d + 3], h2[d + 3], a3);
        }
        h1[o] = fmaxf((a0 + a1) + (a2 + a3), 0.f);   // reuse as h3
    }
    #pragma unroll
    for (int o = 0; o < 6; ++o) {
        float a0 = p[8832 + o], a1 = 0.f, a2 = 0.f, a3 = 0.f;
        #pragma unroll
        for (int d = 0; d < 64; d += 4) {
            a0 = fmaf(p[8448 + o * 64 + d + 0], h1[d + 0], a0);
            a1 = fmaf(p[8448 + o * 64 + d + 1], h1[d + 1], a1);
            a2 = fmaf(p[8448 + o * 64 + d + 2], h1[d + 2], a2);
            a3 = fmaf(p[8448 + o * 64 + d + 3], h1[d + 3], a3);
        }
        out[((size_t)(b * 256 + t)) * 6 + o] = (a0 + a1) + (a2 + a3);
    }
}

// ---------------- host launcher ----------------
extern "C" void kernel_launch(void* const* d_in, const int* in_sizes, int n_in,
                              void* d_out, int out_size, void* d_ws, size_t ws_size,
                              hipStream_t stream)
{
    const float* xs    = (const float*)d_in[0];  // (8,1,256,1)
    const float* ts    = (const float*)d_in[1];  // (8,256)
    const float* theta = (const float*)d_in[2];  // (8838,)
    const float* A     = (const float*)d_in[3];  // (8838,8838)
    const float* B     = (const float*)d_in[4];  // (8838,1)
    float* out = (float*)d_out;

    const size_t GB1 = (size_t)L_ * LP_;                          // 81,451,008 per array
    const size_t VB  = (size_t)NSLOT * L_ * sizeof(float);
    const size_t SB  = (size_t)NSLOT * 8 * sizeof(double);
    const size_t CB  = 256;                                       // c256 (padded)
    const size_t PB  = (size_t)8 * L_ * sizeof(float);
    const size_t SMALL = 2 * VB + SB + CB + PB;
    const size_t FULL  = 2 * GB1 + SMALL;

    if (ws_size < SMALL) return;   // cannot run; fail loudly via validation
    const bool fat = (ws_size >= FULL);

    char* base = (char*)d_ws;
    unsigned char* GHi = (unsigned char*)base;
    unsigned char* GLo = (unsigned char*)(base + GB1);
    size_t off = fat ? 2 * GB1 : 0;
    float*  gv   = (float*)(base + off);  off += VB;
    float*  hv   = (float*)(base + off);  off += VB;
    double* s    = (double*)(base + off); off += SB;
    double* c256 = (double*)(base + off); off += CB;
    float*  pfin = (float*)(base + off);

    // independent of chain -> launch first
    coeff_kernel<<<1, 64, 0, stream>>>(xs, s, c256);

    // slot 0: g_0 = B, h_0 = theta (exact fp32)
    hipMemcpyAsync(gv, B,     L_ * sizeof(float), hipMemcpyDeviceToDevice, stream);
    hipMemcpyAsync(hv, theta, L_ * sizeof(float), hipMemcpyDeviceToDevice, stream);

    if (fat) {
        // pure streaming transcode: A -> int16 split-byte G (no LDS, no dots)
        transcode_kernel<<<dim3(TBLK), dim3(CT), 0, stream>>>(A, GHi, GLo);
        // chain passes p: slot p -> slot p+1 (p<NFULL full precision, else hi-only)
        for (int p = 0; p < MPOW; ++p) {
            const float* gi = gv + (size_t)p * L_;
            const float* hi = hv + (size_t)p * L_;
            float* go = gv + (size_t)(p + 1) * L_;
            float* ho = hv + (size_t)(p + 1) * L_;
            if (p < NFULL)
                chain_pass<true ><<<dim3(CWGRID), dim3(CT), 0, stream>>>(GHi, GLo, gi, hi, go, ho);
            else
                chain_pass<false><<<dim3(CWGRID), dim3(CT), 0, stream>>>(GHi, GLo, gi, hi, go, ho);
        }
    } else {
        for (int p = 0; p < MPOW; ++p)
            chain_fallback<<<dim3(CWGRID), dim3(CT), 0, stream>>>(A,
                gv + (size_t)p * L_,       hv + (size_t)p * L_,
                gv + (size_t)(p + 1) * L_, hv + (size_t)(p + 1) * L_);
    }

    combine_kernel<<<(L_ + 255) / 256, 256, 0, stream>>>(gv, hv, s, c256, pfin);
    mlp_kernel<<<dim3(8, 4), 64, 0, stream>>>(pfin, ts, out);
}